// Round 13
// baseline (143.210 us; speedup 1.0000x reference)
//
#include <hip/hip_runtime.h>

#define B_    64
#define HW_   196
#define HWP_  224
#define D_    768
#define E_    256
#define C_    10
#define MP_   (B_*HWP_)   // 14336 padded rows
#define K3K_  (E_*D_)     // 196608 deep-K for final contraction
#define K3NB_ 256         // k3 blocks (768 k each = one e per block)

typedef _Float16 f16x8 __attribute__((ext_vector_type(8)));
typedef _Float16 f16x4 __attribute__((ext_vector_type(4)));
typedef _Float16 f16x2 __attribute__((ext_vector_type(2)));
typedef float  f32x4  __attribute__((ext_vector_type(4)));

// async global->LDS, 16B per lane; LDS dest is wave-uniform base + lane*16
__device__ __forceinline__ void gld_lds16(const void* g, void* l) {
  __builtin_amdgcn_global_load_lds((const __attribute__((address_space(1))) void*)g,
                                   (__attribute__((address_space(3))) void*)l, 16, 0, 0);
}

// ---------------- K0prep: ag_w -> fp16 (single-term; k1 needs signs only) ----------
__global__ __launch_bounds__(256) void k0_prep(const float* __restrict__ w,
                                               _Float16* __restrict__ w16) {
  size_t i4 = ((size_t)blockIdx.x * 256 + threadIdx.x) * 4;
  float4 v = *(const float4*)&w[i4];
  f16x4 h;
  h[0] = (_Float16)v.x; h[1] = (_Float16)v.y;
  h[2] = (_Float16)v.z; h[3] = (_Float16)v.w;
  *(f16x4*)&w16[i4] = h;
}

// ---------------- K1: sign GEMM, single-term fp16 (R12 version, st now f16) -------
__global__ __launch_bounds__(256) void k1_signs(const float* __restrict__ x,
                                                const _Float16* __restrict__ w16,
                                                const float* __restrict__ bias,
                                                _Float16* __restrict__ st) {
  __shared__ __align__(16) char smem[59392];   // B 3x16KB = 48KB | A 2x5KB = 10KB
  const int m0 = blockIdx.x * 64;
  const int tid = threadIdx.x;
  const int wave = tid >> 6, lane = tid & 63;
  const int wn = wave * 64;                    // e-offset of this wave
  const int q = lane >> 4, l15 = lane & 15;
  const int swq = (q ^ ((l15 >> 1) & 3)) * 8;  // B read-side swizzled k-col

  const int ar = tid >> 2, ac = (tid & 3) * 8;
  const int am = m0 + ar;
  const int ab = am / HWP_;
  const int ahp = am - ab * HWP_;
  const bool avalid = (ahp < HW_);
  const float* aptr = &x[((size_t)ab * HW_ + (avalid ? ahp : 0)) * D_ + ac];

  const int swB = ((tid & 3) ^ ((tid >> 3) & 3)) * 8;   // source-side swizzle
  const size_t offB = (size_t)(tid >> 2) * D_ + swB;

  f32x4 acc[4][4] = {};
  float4 aX0, aX1, aY0, aY1;

#define K1_LOADA(r0, r1, kk) do { \
    r0 = *(const float4*)&aptr[(kk)]; \
    r1 = *(const float4*)&aptr[(kk) + 4]; \
  } while (0)

#define K1_CONV(bufA, r0, r1) do { \
    _Float16* AW = (_Float16*)(smem + 49152 + (bufA) * 5120); \
    float va[8] = {r0.x, r0.y, r0.z, r0.w, r1.x, r1.y, r1.z, r1.w}; \
    f16x8 hh; \
    _Pragma("unroll") \
    for (int j = 0; j < 8; j++) { \
      float vj = avalid ? va[j] : 0.0f; \
      hh[j] = (_Float16)vj; \
    } \
    *(f16x8*)&AW[ar * 40 + ac] = hh; \
  } while (0)

#define K1_DMAB(buf3, kk) do { \
    char* bb = smem + (buf3) * 16384; \
    _Pragma("unroll") \
    for (int c = 0; c < 4; c++) { \
      gld_lds16(&w16[offB + (size_t)c * 64 * D_ + (kk)], bb + c * 4096 + wave * 1024); \
    } \
  } while (0)

#define K1_COMPUTE(buf3, bufA) do { \
    const _Float16* BL = (const _Float16*)(smem + (buf3) * 16384); \
    const _Float16* AL = (const _Float16*)(smem + 49152 + (bufA) * 5120); \
    f16x8 ah[4], bh[4]; \
    _Pragma("unroll") \
    for (int t = 0; t < 4; t++) { \
      ah[t] = *(const f16x8*)&AL[(t * 16 + l15) * 40 + q * 8]; \
      bh[t] = *(const f16x8*)&BL[(wn + t * 16 + l15) * 32 + swq]; \
    } \
    __builtin_amdgcn_s_setprio(1); \
    _Pragma("unroll") \
    for (int mt = 0; mt < 4; mt++) \
      _Pragma("unroll") \
      for (int nt = 0; nt < 4; nt++) \
        acc[mt][nt] = __builtin_amdgcn_mfma_f32_16x16x32_f16(ah[mt], bh[nt], acc[mt][nt], 0, 0, 0); \
    __builtin_amdgcn_s_setprio(0); \
  } while (0)

#define K1_BAR() do { \
    asm volatile("s_waitcnt lgkmcnt(0)" ::: "memory"); \
    __builtin_amdgcn_s_barrier(); \
    __builtin_amdgcn_sched_barrier(0); \
  } while (0)

  K1_DMAB(0, 0);
  __builtin_amdgcn_sched_barrier(0);
  K1_LOADA(aX0, aX1, 0);
  __builtin_amdgcn_sched_barrier(0);
  K1_DMAB(1, 32);
  __builtin_amdgcn_sched_barrier(0);
  K1_LOADA(aY0, aY1, 32);
  K1_CONV(0, aX0, aX1);
  K1_BAR();

#pragma unroll
  for (int t = 0; t < 22; ++t) {
    K1_DMAB((t + 2) % 3, (t + 2) * 32);
    __builtin_amdgcn_sched_barrier(0);
    if ((t & 1) == 0) K1_LOADA(aX0, aX1, (t + 2) * 32);
    else              K1_LOADA(aY0, aY1, (t + 2) * 32);
    K1_COMPUTE(t % 3, t & 1);
    if ((t & 1) == 0) K1_CONV(1, aY0, aY1);
    else              K1_CONV(0, aX0, aX1);
    K1_BAR();
  }
  K1_COMPUTE(22 % 3, 0);
  K1_CONV(1, aY0, aY1);
  K1_BAR();
  K1_COMPUTE(23 % 3, 1);
  K1_BAR();

#undef K1_LOADA
#undef K1_CONV
#undef K1_DMAB
#undef K1_COMPUTE
#undef K1_BAR

  // ---- epilogue: sign+bias -> LDS transpose Sload[e][m] -> coalesced st writes ----
  _Float16* Sload = (_Float16*)smem;     // [256][72] = 36 KB (reuses pipeline pool)
#pragma unroll
  for (int mt = 0; mt < 4; mt++)
#pragma unroll
    for (int nt = 0; nt < 4; nt++) {
      int e = wn + nt * 16 + l15;
      float bv = bias[e];
      f16x4 o;
#pragma unroll
      for (int r = 0; r < 4; r++) {
        int m = m0 + mt * 16 + q * 4 + r;
        int b = m / HWP_;
        int hp = m - b * HWP_;
        float v = acc[mt][nt][r] + bv;
        o[r] = (hp < HW_ && v > 0.0f) ? (_Float16)1.0f : (_Float16)0.0f;
      }
      *(f16x4*)&Sload[e * 72 + mt * 16 + q * 4] = o;
    }
  __syncthreads();
#pragma unroll
  for (int it = 0; it < 16; it++) {
    int e = (tid >> 4) + it * 16;
    int m4 = (tid & 15) * 4;
    f16x4 v = *(const f16x4*)&Sload[e * 72 + m4];
    int mabs = m0 + m4;
    int b = mabs / HWP_;
    int hp = mabs - b * HWP_;
    *(f16x4*)&st[((size_t)b * E_ + e) * HWP_ + hp] = v;
  }
}

// ---------------- K2: G = S^T · X, e-SPLIT (128e x 128d), f16, XCD-grouped --------
// R12 post-mortem: k2's 19% occupancy was GRID-capped (384 blocks / 256 CU = 1.5).
// Now 768 blocks (2 e-halves x 6 d-slices x 64 b), 256 threads, 36 KB LDS ->
// 3 blocks/CU average, 4 co-resident by LDS. All 12 tiles of a batch b share one
// XCD (bijective f&7 mapping) so st[b] and x[b] stay L2-local.
__global__ __launch_bounds__(256) void k2_g(const _Float16* __restrict__ st,
                                            const float* __restrict__ x,
                                            _Float16* __restrict__ g) {
  __shared__ __align__(16) _Float16 As[2][128 * 32];   // 16 KB
  __shared__ __align__(16) _Float16 Bs[2][128 * 40];   // 20 KB, Bs[d][k] stride 40
  const int f = blockIdx.x;                // 0..767
  const int xcd = f & 7;
  const int s = f >> 3;                    // 0..95
  const int b  = xcd + 8 * (s / 12);
  const int r12 = s % 12;
  const int eh = r12 / 6;                  // e-half
  const int d0 = (r12 % 6) * 128;
  const int tid = threadIdx.x;
  const int wave = tid >> 6, lane = tid & 63;
  const int WEl = (wave & 1) * 64;         // e-offset within 128 (LDS-local)
  const int WD  = (wave >> 1) * 64;        // d-offset within 128
  const int q = lane >> 4, l15 = lane & 15;
  const int ar = tid >> 2, ac = (tid & 3) * 8;   // As staging: row 0..63 (+64), 8 k
  const int ldA = wave * 512;
  const int dg = tid & 31, kp = tid >> 5;  // Bs staging: 4d x 4hp per thread
  f32x4 acc[4][4] = {};

  const _Float16* gA = &st[((size_t)b * E_ + eh * 128 + ar) * HWP_ + ac];
  const float4 zero4 = make_float4(0.f, 0.f, 0.f, 0.f);
  float4 f0, f1, f2, f3;

#define K2_STAGEA(buf, kk) do { \
    gld_lds16(gA + (kk),                      &As[buf][ldA]); \
    gld_lds16(gA + (size_t)64 * HWP_ + (kk),  &As[buf][2048 + ldA]); \
  } while (0)

#define K2_LOADB(kk) do { \
    int hp0 = (kk) + 4 * kp; \
    const float* bsrc = &x[((size_t)b * HW_ + hp0) * D_ + d0 + 4 * dg]; \
    f0 = (hp0     < HW_) ? *(const float4*)&bsrc[0]      : zero4; \
    f1 = (hp0 + 1 < HW_) ? *(const float4*)&bsrc[D_]     : zero4; \
    f2 = (hp0 + 2 < HW_) ? *(const float4*)&bsrc[2 * D_] : zero4; \
    f3 = (hp0 + 3 < HW_) ? *(const float4*)&bsrc[3 * D_] : zero4; \
  } while (0)

#define K2_WRITEB(buf) do { \
    float rr0[4] = {f0.x, f0.y, f0.z, f0.w}; \
    float rr1[4] = {f1.x, f1.y, f1.z, f1.w}; \
    float rr2[4] = {f2.x, f2.y, f2.z, f2.w}; \
    float rr3[4] = {f3.x, f3.y, f3.z, f3.w}; \
    _Pragma("unroll") \
    for (int j = 0; j < 4; j++) { \
      f16x4 o; \
      o[0] = (_Float16)rr0[j]; o[1] = (_Float16)rr1[j]; \
      o[2] = (_Float16)rr2[j]; o[3] = (_Float16)rr3[j]; \
      *(f16x4*)&Bs[buf][(4 * dg + j) * 40 + 4 * kp] = o; \
    } \
  } while (0)

  K2_STAGEA(0, 0);
  K2_LOADB(0);
  K2_WRITEB(0);
  __syncthreads();

  int cur = 0;
  for (int k0 = 0; k0 < HWP_; k0 += 32) {
    const bool have = (k0 + 32 < HWP_);
    if (have) {
      K2_STAGEA(cur ^ 1, k0 + 32);
      K2_LOADB(k0 + 32);
    }
    f16x8 af[4], bfr[4];
#pragma unroll
    for (int t = 0; t < 4; t++) {
      af[t]  = *(const f16x8*)&As[cur][(WEl + t * 16 + l15) * 32 + q * 8];
      bfr[t] = *(const f16x8*)&Bs[cur][(WD + t * 16 + l15) * 40 + q * 8];
    }
#pragma unroll
    for (int mt = 0; mt < 4; mt++)
#pragma unroll
      for (int nt = 0; nt < 4; nt++)
        acc[mt][nt] = __builtin_amdgcn_mfma_f32_16x16x32_f16(af[mt], bfr[nt], acc[mt][nt], 0, 0, 0);
    if (have) K2_WRITEB(cur ^ 1);
    __syncthreads();
    cur ^= 1;
  }
#undef K2_STAGEA
#undef K2_LOADB
#undef K2_WRITEB

#pragma unroll
  for (int mt = 0; mt < 4; mt++)
#pragma unroll
    for (int nt = 0; nt < 4; nt++) {
      int d = d0 + WD + nt * 16 + l15;
#pragma unroll
      for (int r = 0; r < 4; r++) {
        int e = eh * 128 + WEl + mt * 16 + q * 4 + r;
        g[((size_t)b * E_ + e) * D_ + d] = (_Float16)acc[mt][nt][r];
      }
    }
}

// ---------------- K3: partials, 512 threads (8 waves -> 2x load depth), f16 -------
__global__ __launch_bounds__(512) void k3_mfma(const _Float16* __restrict__ g,
                                               const float* __restrict__ lmw,
                                               float* __restrict__ part) {
  __shared__ float sp[B_ * C_];
  const int tid = threadIdx.x;
  const int wave = tid >> 6, lane = tid & 63;
  const int q = lane >> 4, l15 = lane & 15;
  const int e = blockIdx.x;                 // 0..255
  f32x4 acc[4] = {};

  for (int i = tid; i < B_ * C_; i += 512) sp[i] = 0.0f;

#pragma unroll
  for (int ks = 0; ks < 3; ks++) {
    int d = wave * 96 + ks * 32 + q * 8;
    size_t k = (size_t)e * D_ + d;
    f16x8 bfrag;
    if (l15 < C_) {
      const float* bp = &lmw[((size_t)e * C_ + l15) * D_ + d];
      float4 b0 = *(const float4*)&bp[0];
      float4 b1 = *(const float4*)&bp[4];
      float bb[8] = {b0.x, b0.y, b0.z, b0.w, b1.x, b1.y, b1.z, b1.w};
#pragma unroll
      for (int j = 0; j < 8; j++) bfrag[j] = (_Float16)bb[j];
    } else {
#pragma unroll
      for (int j = 0; j < 8; j++) bfrag[j] = (_Float16)0.0f;
    }
#pragma unroll
    for (int mt = 0; mt < 4; mt++) {
      f16x8 afrag = *(const f16x8*)&g[(size_t)(mt * 16 + l15) * K3K_ + k];
      acc[mt] = __builtin_amdgcn_mfma_f32_16x16x32_f16(afrag, bfrag, acc[mt], 0, 0, 0);
    }
  }
  __syncthreads();
  if (l15 < C_) {
#pragma unroll
    for (int mt = 0; mt < 4; mt++)
#pragma unroll
      for (int r = 0; r < 4; r++) {
        int b = mt * 16 + q * 4 + r;
        atomicAdd(&sp[b * C_ + l15], acc[mt][r]);   // LDS atomics only
      }
  }
  __syncthreads();
  for (int i = tid; i < B_ * C_; i += 512)
    part[(size_t)blockIdx.x * (B_ * C_) + i] = sp[i];
}

// ---------------- K4: reduce 256 partials -> out ----------------
__global__ __launch_bounds__(256) void k4_reduce(const float* __restrict__ part,
                                                 float* __restrict__ out) {
  __shared__ float sp[256];
  const int b = blockIdx.x;
  const int tid = threadIdx.x;
  const int c = tid & 15, g16 = tid >> 4;   // 16 groups x 16 c-slots
  float s = 0.0f;
  if (c < C_) {
#pragma unroll
    for (int j = 0; j < 16; j++)
      s += part[(size_t)(g16 + 16 * j) * (B_ * C_) + b * C_ + c];
  }
  sp[tid] = s;
  __syncthreads();
  if (tid < C_) {
    float t = 0.0f;
#pragma unroll
    for (int j = 0; j < 16; j++) t += sp[j * 16 + tid];
    out[b * C_ + tid] = t * (1.0f / (196.0f * 256.0f));
  }
}

extern "C" void kernel_launch(void* const* d_in, const int* in_sizes, int n_in,
                              void* d_out, int out_size, void* d_ws, size_t ws_size,
                              hipStream_t stream) {
  const float* x    = (const float*)d_in[0];   // (64,196,768)
  const float* ag_w = (const float*)d_in[1];   // (256,768)
  const float* ag_b = (const float*)d_in[2];   // (256,)
  const float* lm_w = (const float*)d_in[3];   // (2560,768)
  float* out = (float*)d_out;                  // (64,10)

  char* ws = (char*)d_ws;
  const size_t W_BYTES  = (size_t)E_ * D_ * 2;
  const size_t ST_BYTES = (size_t)B_ * E_ * HWP_ * 2;
  const size_t G_BYTES  = (size_t)B_ * E_ * D_ * 2;
  _Float16* w16 = (_Float16*)(ws);
  _Float16* st  = (_Float16*)(ws + W_BYTES);
  _Float16* gb  = (_Float16*)(ws + W_BYTES + ST_BYTES);
  float*  part  = (float*)(ws + W_BYTES + ST_BYTES + G_BYTES);

  k0_prep<<<dim3((E_ * D_) / 4 / 256), dim3(256), 0, stream>>>(ag_w, w16);
  k1_signs<<<dim3(MP_ / 64), dim3(256), 0, stream>>>(x, w16, ag_b, st);
  k2_g<<<dim3(12 * B_), dim3(256), 0, stream>>>(st, x, gb);
  k3_mfma<<<dim3(K3NB_), dim3(512), 0, stream>>>(gb, lm_w, part);
  k4_reduce<<<dim3(B_), dim3(256), 0, stream>>>(part, out);
}

// Round 14
// 140.945 us; speedup vs baseline: 1.0161x; 1.0161x over previous
//
#include <hip/hip_runtime.h>

#define B_    64
#define HW_   196
#define HWP_  224
#define D_    768
#define E_    256
#define C_    10
#define MP_   (B_*HWP_)   // 14336 padded rows
#define K3K_  (E_*D_)     // 196608 deep-K for final contraction
#define K3NB_ 256         // k3 blocks (768 k each = one e per block)

typedef _Float16 f16x8 __attribute__((ext_vector_type(8)));
typedef _Float16 f16x4 __attribute__((ext_vector_type(4)));
typedef _Float16 f16x2 __attribute__((ext_vector_type(2)));
typedef float  f32x4  __attribute__((ext_vector_type(4)));

// async global->LDS, 16B per lane; LDS dest is wave-uniform base + lane*16
__device__ __forceinline__ void gld_lds16(const void* g, void* l) {
  __builtin_amdgcn_global_load_lds((const __attribute__((address_space(1))) void*)g,
                                   (__attribute__((address_space(3))) void*)l, 16, 0, 0);
}

// ---------------- K0prep: ag_w -> fp16 (single-term; k1 needs signs only) ----------
__global__ __launch_bounds__(256) void k0_prep(const float* __restrict__ w,
                                               _Float16* __restrict__ w16) {
  size_t i4 = ((size_t)blockIdx.x * 256 + threadIdx.x) * 4;
  float4 v = *(const float4*)&w[i4];
  f16x4 h;
  h[0] = (_Float16)v.x; h[1] = (_Float16)v.y;
  h[2] = (_Float16)v.z; h[3] = (_Float16)v.w;
  *(f16x4*)&w16[i4] = h;
}

// ---------------- K1: sign GEMM, fp16; ALSO emits padded xf16 for k2 --------------
// x is converted to f16 here anyway for A-staging; writing it out (22 MB, padded
// [b][HWP][D], zeros for hp>=HW) halves k2's x read. Bit-identical to k2's old
// in-kernel conversion. Pipeline structure = R12/R13 (depth-2, drain-free).
__global__ __launch_bounds__(256) void k1_signs(const float* __restrict__ x,
                                                const _Float16* __restrict__ w16,
                                                const float* __restrict__ bias,
                                                _Float16* __restrict__ st,
                                                _Float16* __restrict__ xf) {
  __shared__ __align__(16) char smem[59392];   // B 3x16KB = 48KB | A 2x5KB = 10KB
  const int m0 = blockIdx.x * 64;
  const int tid = threadIdx.x;
  const int wave = tid >> 6, lane = tid & 63;
  const int wn = wave * 64;                    // e-offset of this wave
  const int q = lane >> 4, l15 = lane & 15;
  const int swq = (q ^ ((l15 >> 1) & 3)) * 8;  // B read-side swizzled k-col

  const int ar = tid >> 2, ac = (tid & 3) * 8;
  const int am = m0 + ar;
  const int ab = am / HWP_;
  const int ahp = am - ab * HWP_;
  const bool avalid = (ahp < HW_);
  const float* aptr = &x[((size_t)ab * HW_ + (avalid ? ahp : 0)) * D_ + ac];

  const int swB = ((tid & 3) ^ ((tid >> 3) & 3)) * 8;   // source-side swizzle
  const size_t offB = (size_t)(tid >> 2) * D_ + swB;

  f32x4 acc[4][4] = {};
  float4 aX0, aX1, aY0, aY1;

#define K1_LOADA(r0, r1, kk) do { \
    r0 = *(const float4*)&aptr[(kk)]; \
    r1 = *(const float4*)&aptr[(kk) + 4]; \
  } while (0)

#define K1_CONV(bufA, r0, r1, kk) do { \
    _Float16* AW = (_Float16*)(smem + 49152 + (bufA) * 5120); \
    float va[8] = {r0.x, r0.y, r0.z, r0.w, r1.x, r1.y, r1.z, r1.w}; \
    f16x8 hh; \
    _Pragma("unroll") \
    for (int j = 0; j < 8; j++) { \
      float vj = avalid ? va[j] : 0.0f; \
      hh[j] = (_Float16)vj; \
    } \
    *(f16x8*)&AW[ar * 40 + ac] = hh; \
    *(f16x8*)&xf[(size_t)am * D_ + (kk) + ac] = hh; \
  } while (0)

#define K1_DMAB(buf3, kk) do { \
    char* bb = smem + (buf3) * 16384; \
    _Pragma("unroll") \
    for (int c = 0; c < 4; c++) { \
      gld_lds16(&w16[offB + (size_t)c * 64 * D_ + (kk)], bb + c * 4096 + wave * 1024); \
    } \
  } while (0)

#define K1_COMPUTE(buf3, bufA) do { \
    const _Float16* BL = (const _Float16*)(smem + (buf3) * 16384); \
    const _Float16* AL = (const _Float16*)(smem + 49152 + (bufA) * 5120); \
    f16x8 ah[4], bh[4]; \
    _Pragma("unroll") \
    for (int t = 0; t < 4; t++) { \
      ah[t] = *(const f16x8*)&AL[(t * 16 + l15) * 40 + q * 8]; \
      bh[t] = *(const f16x8*)&BL[(wn + t * 16 + l15) * 32 + swq]; \
    } \
    __builtin_amdgcn_s_setprio(1); \
    _Pragma("unroll") \
    for (int mt = 0; mt < 4; mt++) \
      _Pragma("unroll") \
      for (int nt = 0; nt < 4; nt++) \
        acc[mt][nt] = __builtin_amdgcn_mfma_f32_16x16x32_f16(ah[mt], bh[nt], acc[mt][nt], 0, 0, 0); \
    __builtin_amdgcn_s_setprio(0); \
  } while (0)

#define K1_BAR() do { \
    asm volatile("s_waitcnt lgkmcnt(0)" ::: "memory"); \
    __builtin_amdgcn_s_barrier(); \
    __builtin_amdgcn_sched_barrier(0); \
  } while (0)

  K1_DMAB(0, 0);
  __builtin_amdgcn_sched_barrier(0);
  K1_LOADA(aX0, aX1, 0);
  __builtin_amdgcn_sched_barrier(0);
  K1_DMAB(1, 32);
  __builtin_amdgcn_sched_barrier(0);
  K1_LOADA(aY0, aY1, 32);
  K1_CONV(0, aX0, aX1, 0);
  K1_BAR();

#pragma unroll
  for (int t = 0; t < 22; ++t) {
    K1_DMAB((t + 2) % 3, (t + 2) * 32);
    __builtin_amdgcn_sched_barrier(0);
    if ((t & 1) == 0) K1_LOADA(aX0, aX1, (t + 2) * 32);
    else              K1_LOADA(aY0, aY1, (t + 2) * 32);
    K1_COMPUTE(t % 3, t & 1);
    if ((t & 1) == 0) K1_CONV(1, aY0, aY1, (t + 1) * 32);
    else              K1_CONV(0, aX0, aX1, (t + 1) * 32);
    K1_BAR();
  }
  K1_COMPUTE(22 % 3, 0);
  K1_CONV(1, aY0, aY1, 23 * 32);
  K1_BAR();
  K1_COMPUTE(23 % 3, 1);
  K1_BAR();

#undef K1_LOADA
#undef K1_CONV
#undef K1_DMAB
#undef K1_COMPUTE
#undef K1_BAR

  // ---- epilogue: sign+bias -> LDS transpose Sload[e][m] -> coalesced st writes ----
  _Float16* Sload = (_Float16*)smem;     // [256][72] = 36 KB (reuses pipeline pool)
#pragma unroll
  for (int mt = 0; mt < 4; mt++)
#pragma unroll
    for (int nt = 0; nt < 4; nt++) {
      int e = wn + nt * 16 + l15;
      float bv = bias[e];
      f16x4 o;
#pragma unroll
      for (int r = 0; r < 4; r++) {
        int m = m0 + mt * 16 + q * 4 + r;
        int b = m / HWP_;
        int hp = m - b * HWP_;
        float v = acc[mt][nt][r] + bv;
        o[r] = (hp < HW_ && v > 0.0f) ? (_Float16)1.0f : (_Float16)0.0f;
      }
      *(f16x4*)&Sload[e * 72 + mt * 16 + q * 4] = o;
    }
  __syncthreads();
#pragma unroll
  for (int it = 0; it < 16; it++) {
    int e = (tid >> 4) + it * 16;
    int m4 = (tid & 15) * 4;
    f16x4 v = *(const f16x4*)&Sload[e * 72 + m4];
    int mabs = m0 + m4;
    int b = mabs / HWP_;
    int hp = mabs - b * HWP_;
    *(f16x4*)&st[((size_t)b * E_ + e) * HWP_ + hp] = v;
  }
}

// ---------------- K2: G = S^T · X, e-SPLIT (128e x 128d), f16 source --------------
// B now reads the padded f16 xf (22 MB, half of fp32 x) with NO hp guards
// (padding rows are real zeros). Staging geometry identical to R13.
__global__ __launch_bounds__(256) void k2_g(const _Float16* __restrict__ st,
                                            const _Float16* __restrict__ xf,
                                            _Float16* __restrict__ g) {
  __shared__ __align__(16) _Float16 As[2][128 * 32];   // 16 KB
  __shared__ __align__(16) _Float16 Bs[2][128 * 40];   // 20 KB, Bs[d][k] stride 40
  const int f = blockIdx.x;                // 0..767
  const int xcd = f & 7;
  const int s = f >> 3;                    // 0..95
  const int b  = xcd + 8 * (s / 12);
  const int r12 = s % 12;
  const int eh = r12 / 6;                  // e-half
  const int d0 = (r12 % 6) * 128;
  const int tid = threadIdx.x;
  const int wave = tid >> 6, lane = tid & 63;
  const int WEl = (wave & 1) * 64;         // e-offset within 128 (LDS-local)
  const int WD  = (wave >> 1) * 64;        // d-offset within 128
  const int q = lane >> 4, l15 = lane & 15;
  const int ar = tid >> 2, ac = (tid & 3) * 8;   // As staging: row 0..63 (+64), 8 k
  const int ldA = wave * 512;
  const int dg = tid & 31, kp = tid >> 5;  // Bs staging: 4d x 4hp per thread
  f32x4 acc[4][4] = {};

  const _Float16* gA = &st[((size_t)b * E_ + eh * 128 + ar) * HWP_ + ac];
  f16x4 h0, h1, h2, h3;

#define K2_STAGEA(buf, kk) do { \
    gld_lds16(gA + (kk),                      &As[buf][ldA]); \
    gld_lds16(gA + (size_t)64 * HWP_ + (kk),  &As[buf][2048 + ldA]); \
  } while (0)

#define K2_LOADB(kk) do { \
    const _Float16* bsrc = &xf[((size_t)b * HWP_ + (kk) + 4 * kp) * D_ + d0 + 4 * dg]; \
    h0 = *(const f16x4*)&bsrc[0]; \
    h1 = *(const f16x4*)&bsrc[D_]; \
    h2 = *(const f16x4*)&bsrc[2 * D_]; \
    h3 = *(const f16x4*)&bsrc[3 * D_]; \
  } while (0)

#define K2_WRITEB(buf) do { \
    _Pragma("unroll") \
    for (int j = 0; j < 4; j++) { \
      f16x4 o; \
      o[0] = h0[j]; o[1] = h1[j]; o[2] = h2[j]; o[3] = h3[j]; \
      *(f16x4*)&Bs[buf][(4 * dg + j) * 40 + 4 * kp] = o; \
    } \
  } while (0)

  K2_STAGEA(0, 0);
  K2_LOADB(0);
  K2_WRITEB(0);
  __syncthreads();

  int cur = 0;
  for (int k0 = 0; k0 < HWP_; k0 += 32) {
    const bool have = (k0 + 32 < HWP_);
    if (have) {
      K2_STAGEA(cur ^ 1, k0 + 32);
      K2_LOADB(k0 + 32);
    }
    f16x8 af[4], bfr[4];
#pragma unroll
    for (int t = 0; t < 4; t++) {
      af[t]  = *(const f16x8*)&As[cur][(WEl + t * 16 + l15) * 32 + q * 8];
      bfr[t] = *(const f16x8*)&Bs[cur][(WD + t * 16 + l15) * 40 + q * 8];
    }
#pragma unroll
    for (int mt = 0; mt < 4; mt++)
#pragma unroll
      for (int nt = 0; nt < 4; nt++)
        acc[mt][nt] = __builtin_amdgcn_mfma_f32_16x16x32_f16(af[mt], bfr[nt], acc[mt][nt], 0, 0, 0);
    if (have) K2_WRITEB(cur ^ 1);
    __syncthreads();
    cur ^= 1;
  }
#undef K2_STAGEA
#undef K2_LOADB
#undef K2_WRITEB

#pragma unroll
  for (int mt = 0; mt < 4; mt++)
#pragma unroll
    for (int nt = 0; nt < 4; nt++) {
      int d = d0 + WD + nt * 16 + l15;
#pragma unroll
      for (int r = 0; r < 4; r++) {
        int e = eh * 128 + WEl + mt * 16 + q * 4 + r;
        g[((size_t)b * E_ + e) * D_ + d] = (_Float16)acc[mt][nt][r];
      }
    }
}

// ---------------- K3: partials, 512 threads, lm_w on the fly, f16 -----------------
__global__ __launch_bounds__(512) void k3_mfma(const _Float16* __restrict__ g,
                                               const float* __restrict__ lmw,
                                               float* __restrict__ part) {
  __shared__ float sp[B_ * C_];
  const int tid = threadIdx.x;
  const int wave = tid >> 6, lane = tid & 63;
  const int q = lane >> 4, l15 = lane & 15;
  const int e = blockIdx.x;                 // 0..255
  f32x4 acc[4] = {};

  for (int i = tid; i < B_ * C_; i += 512) sp[i] = 0.0f;

#pragma unroll
  for (int ks = 0; ks < 3; ks++) {
    int d = wave * 96 + ks * 32 + q * 8;
    size_t k = (size_t)e * D_ + d;
    f16x8 bfrag;
    if (l15 < C_) {
      const float* bp = &lmw[((size_t)e * C_ + l15) * D_ + d];
      float4 b0 = *(const float4*)&bp[0];
      float4 b1 = *(const float4*)&bp[4];
      float bb[8] = {b0.x, b0.y, b0.z, b0.w, b1.x, b1.y, b1.z, b1.w};
#pragma unroll
      for (int j = 0; j < 8; j++) bfrag[j] = (_Float16)bb[j];
    } else {
#pragma unroll
      for (int j = 0; j < 8; j++) bfrag[j] = (_Float16)0.0f;
    }
#pragma unroll
    for (int mt = 0; mt < 4; mt++) {
      f16x8 afrag = *(const f16x8*)&g[(size_t)(mt * 16 + l15) * K3K_ + k];
      acc[mt] = __builtin_amdgcn_mfma_f32_16x16x32_f16(afrag, bfrag, acc[mt], 0, 0, 0);
    }
  }
  __syncthreads();
  if (l15 < C_) {
#pragma unroll
    for (int mt = 0; mt < 4; mt++)
#pragma unroll
      for (int r = 0; r < 4; r++) {
        int b = mt * 16 + q * 4 + r;
        atomicAdd(&sp[b * C_ + l15], acc[mt][r]);   // LDS atomics only
      }
  }
  __syncthreads();
  for (int i = tid; i < B_ * C_; i += 512)
    part[(size_t)blockIdx.x * (B_ * C_) + i] = sp[i];
}

// ---------------- K4: reduce 256 partials -> out ----------------
__global__ __launch_bounds__(256) void k4_reduce(const float* __restrict__ part,
                                                 float* __restrict__ out) {
  __shared__ float sp[256];
  const int b = blockIdx.x;
  const int tid = threadIdx.x;
  const int c = tid & 15, g16 = tid >> 4;   // 16 groups x 16 c-slots
  float s = 0.0f;
  if (c < C_) {
#pragma unroll
    for (int j = 0; j < 16; j++)
      s += part[(size_t)(g16 + 16 * j) * (B_ * C_) + b * C_ + c];
  }
  sp[tid] = s;
  __syncthreads();
  if (tid < C_) {
    float t = 0.0f;
#pragma unroll
    for (int j = 0; j < 16; j++) t += sp[j * 16 + tid];
    out[b * C_ + tid] = t * (1.0f / (196.0f * 256.0f));
  }
}

extern "C" void kernel_launch(void* const* d_in, const int* in_sizes, int n_in,
                              void* d_out, int out_size, void* d_ws, size_t ws_size,
                              hipStream_t stream) {
  const float* x    = (const float*)d_in[0];   // (64,196,768)
  const float* ag_w = (const float*)d_in[1];   // (256,768)
  const float* ag_b = (const float*)d_in[2];   // (256,)
  const float* lm_w = (const float*)d_in[3];   // (2560,768)
  float* out = (float*)d_out;                  // (64,10)

  char* ws = (char*)d_ws;
  const size_t W_BYTES  = (size_t)E_ * D_ * 2;
  const size_t ST_BYTES = (size_t)B_ * E_ * HWP_ * 2;
  const size_t G_BYTES  = (size_t)B_ * E_ * D_ * 2;
  const size_t XF_BYTES = (size_t)MP_ * D_ * 2;          // 22 MB padded f16 x
  _Float16* w16 = (_Float16*)(ws);
  _Float16* st  = (_Float16*)(ws + W_BYTES);
  _Float16* gb  = (_Float16*)(ws + W_BYTES + ST_BYTES);
  _Float16* xf  = (_Float16*)(ws + W_BYTES + ST_BYTES + G_BYTES);
  float*  part  = (float*)(ws + W_BYTES + ST_BYTES + G_BYTES + XF_BYTES);

  k0_prep<<<dim3((E_ * D_) / 4 / 256), dim3(256), 0, stream>>>(ag_w, w16);
  k1_signs<<<dim3(MP_ / 64), dim3(256), 0, stream>>>(x, w16, ag_b, st, xf);
  k2_g<<<dim3(12 * B_), dim3(256), 0, stream>>>(st, xf, gb);
  k3_mfma<<<dim3(K3NB_), dim3(512), 0, stream>>>(gb, lm_w, part);
  k4_reduce<<<dim3(B_), dim3(256), 0, stream>>>(part, out);
}

// Round 15
// 131.770 us; speedup vs baseline: 1.0868x; 1.0696x over previous
//
#include <hip/hip_runtime.h>

#define B_    64
#define HW_   196
#define HWP_  224
#define D_    768
#define E_    256
#define C_    10
#define MP_   (B_*HWP_)   // 14336 padded rows
#define K3K_  (E_*D_)     // 196608 deep-K for final contraction
#define K3NB_ 256         // k3 blocks (768 k each = one e per block)

typedef _Float16 f16x8 __attribute__((ext_vector_type(8)));
typedef _Float16 f16x4 __attribute__((ext_vector_type(4)));
typedef float  f32x4  __attribute__((ext_vector_type(4)));

// async global->LDS, 16B per lane; LDS dest is wave-uniform base + lane*16
__device__ __forceinline__ void gld_lds16(const void* g, void* l) {
  __builtin_amdgcn_global_load_lds((const __attribute__((address_space(1))) void*)g,
                                   (__attribute__((address_space(3))) void*)l, 16, 0, 0);
}

// ---------------- K0prep: streaming {x -> padded f16 xf} + {ag_w -> f16 w16} -------
// Pure streaming (fills/copies run ~6.3 TB/s on this chip). xf rows hp>=HW are
// real zeros, so k1/k2 need no guards. Conversion identical to k1's old in-reg
// cast -> downstream results bit-identical to R14.
__global__ __launch_bounds__(256) void k0_prep(const float* __restrict__ x,
                                               const float* __restrict__ w,
                                               _Float16* __restrict__ xf,
                                               _Float16* __restrict__ w16) {
  int bid = blockIdx.x;
  if (bid < 192) {
    size_t i4 = ((size_t)bid * 256 + threadIdx.x) * 4;
    float4 v = *(const float4*)&w[i4];
    f16x4 h;
    h[0] = (_Float16)v.x; h[1] = (_Float16)v.y;
    h[2] = (_Float16)v.z; h[3] = (_Float16)v.w;
    *(f16x4*)&w16[i4] = h;
  } else {
    size_t i4 = ((size_t)(bid - 192) * 256 + threadIdx.x) * 4;  // < MP_*D_
    int d = (int)(i4 % D_);
    size_t row = i4 / D_;
    int hp = (int)(row % HWP_);
    int b  = (int)(row / HWP_);
    float4 v = make_float4(0.f, 0.f, 0.f, 0.f);
    if (hp < HW_) v = *(const float4*)&x[((size_t)b * HW_ + hp) * D_ + d];
    f16x4 h;
    h[0] = (_Float16)v.x; h[1] = (_Float16)v.y;
    h[2] = (_Float16)v.z; h[3] = (_Float16)v.w;
    *(f16x4*)&xf[i4] = h;
  }
}

// ---------------- K1: sign GEMM, ALL-DMA operands, counted-vmcnt pipeline ----------
// A (from xf, L3-hot, padded -> no guards) and B (w16) both via global_load_lds,
// 3-deep buffers, issued 2 steps ahead. Before each raw barrier: s_waitcnt
// vmcnt(5) retires exactly tile-(t+1)'s 5 DMAs (4 B + 1 A), keeping tile-(t+2)'s
// in flight (R8's ordering guarantee, now explicit since the A-conv waits are
// gone). Both operands use the R12-proven involution swizzle (2-way banked).
// No float4 loads, no cvt, no xf store -- leanest possible step.
__global__ __launch_bounds__(256) void k1_signs(const _Float16* __restrict__ xf,
                                                const _Float16* __restrict__ w16,
                                                const float* __restrict__ bias,
                                                _Float16* __restrict__ st) {
  __shared__ __align__(16) char smem[61440];   // B 3x16KB = 48KB | A 3x4KB = 12KB
  const int m0 = blockIdx.x * 64;
  const int tid = threadIdx.x;
  const int wave = tid >> 6, lane = tid & 63;
  const int wn = wave * 64;                    // e-offset of this wave
  const int q = lane >> 4, l15 = lane & 15;
  const int swq = (q ^ ((l15 >> 1) & 3)) * 8;  // read-side swizzled k-col (A and B)

  const int sw = ((tid & 3) ^ ((tid >> 3) & 3)) * 8;   // source-side swizzle
  const size_t offA = (size_t)(m0 + (tid >> 2)) * D_ + sw;   // xf padded: no guard
  const size_t offB = (size_t)(tid >> 2) * D_ + sw;

  f32x4 acc[4][4] = {};

#define K1_DMA(buf3, kk) do { \
    char* bb = smem + (buf3) * 16384; \
    _Pragma("unroll") \
    for (int c = 0; c < 4; c++) \
      gld_lds16(&w16[offB + (size_t)c * 64 * D_ + (kk)], bb + c * 4096 + wave * 1024); \
    gld_lds16(&xf[offA + (kk)], smem + 49152 + (buf3) * 4096 + wave * 1024); \
  } while (0)

#define K1_COMPUTE(buf3) do { \
    const _Float16* BL = (const _Float16*)(smem + (buf3) * 16384); \
    const _Float16* AL = (const _Float16*)(smem + 49152 + (buf3) * 4096); \
    f16x8 ah[4], bh[4]; \
    _Pragma("unroll") \
    for (int t = 0; t < 4; t++) { \
      ah[t] = *(const f16x8*)&AL[(t * 16 + l15) * 32 + swq]; \
      bh[t] = *(const f16x8*)&BL[(wn + t * 16 + l15) * 32 + swq]; \
    } \
    __builtin_amdgcn_s_setprio(1); \
    _Pragma("unroll") \
    for (int mt = 0; mt < 4; mt++) \
      _Pragma("unroll") \
      for (int nt = 0; nt < 4; nt++) \
        acc[mt][nt] = __builtin_amdgcn_mfma_f32_16x16x32_f16(ah[mt], bh[nt], acc[mt][nt], 0, 0, 0); \
    __builtin_amdgcn_s_setprio(0); \
  } while (0)

  // prologue: stage tiles 0 and 1; retire tile 0 (keep tile 1 in flight)
  K1_DMA(0, 0);
  K1_DMA(1, 32);
  asm volatile("s_waitcnt vmcnt(5)" ::: "memory");
  __builtin_amdgcn_s_barrier();
  __builtin_amdgcn_sched_barrier(0);

#pragma unroll
  for (int t = 0; t < 24; ++t) {
    if (t + 2 < 24) K1_DMA((t + 2) % 3, (t + 2) * 32);
    __builtin_amdgcn_sched_barrier(0);
    K1_COMPUTE(t % 3);
    if (t + 2 < 24) asm volatile("s_waitcnt vmcnt(5) lgkmcnt(0)" ::: "memory");
    else            asm volatile("s_waitcnt vmcnt(0) lgkmcnt(0)" ::: "memory");
    __builtin_amdgcn_s_barrier();
    __builtin_amdgcn_sched_barrier(0);
  }
#undef K1_DMA
#undef K1_COMPUTE

  // ---- epilogue: sign+bias -> LDS transpose Sload[e][m] -> coalesced st writes ----
  _Float16* Sload = (_Float16*)smem;     // [256][72] = 36 KB (reuses pipeline pool)
#pragma unroll
  for (int mt = 0; mt < 4; mt++)
#pragma unroll
    for (int nt = 0; nt < 4; nt++) {
      int e = wn + nt * 16 + l15;
      float bv = bias[e];
      f16x4 o;
#pragma unroll
      for (int r = 0; r < 4; r++) {
        int m = m0 + mt * 16 + q * 4 + r;
        int b = m / HWP_;
        int hp = m - b * HWP_;
        float v = acc[mt][nt][r] + bv;
        o[r] = (hp < HW_ && v > 0.0f) ? (_Float16)1.0f : (_Float16)0.0f;
      }
      *(f16x4*)&Sload[e * 72 + mt * 16 + q * 4] = o;
    }
  __syncthreads();
#pragma unroll
  for (int it = 0; it < 16; it++) {
    int e = (tid >> 4) + it * 16;
    int m4 = (tid & 15) * 4;
    f16x4 v = *(const f16x4*)&Sload[e * 72 + m4];
    int mabs = m0 + m4;
    int b = mabs / HWP_;
    int hp = mabs - b * HWP_;
    *(f16x4*)&st[((size_t)b * E_ + e) * HWP_ + hp] = v;
  }
}

// ---------------- K2: G = S^T · X, e-SPLIT (128e x 128d), f16 source (R14) --------
__global__ __launch_bounds__(256) void k2_g(const _Float16* __restrict__ st,
                                            const _Float16* __restrict__ xf,
                                            _Float16* __restrict__ g) {
  __shared__ __align__(16) _Float16 As[2][128 * 32];   // 16 KB
  __shared__ __align__(16) _Float16 Bs[2][128 * 40];   // 20 KB, Bs[d][k] stride 40
  const int f = blockIdx.x;                // 0..767
  const int xcd = f & 7;
  const int s = f >> 3;                    // 0..95
  const int b  = xcd + 8 * (s / 12);
  const int r12 = s % 12;
  const int eh = r12 / 6;                  // e-half
  const int d0 = (r12 % 6) * 128;
  const int tid = threadIdx.x;
  const int wave = tid >> 6, lane = tid & 63;
  const int WEl = (wave & 1) * 64;         // e-offset within 128 (LDS-local)
  const int WD  = (wave >> 1) * 64;        // d-offset within 128
  const int q = lane >> 4, l15 = lane & 15;
  const int ar = tid >> 2, ac = (tid & 3) * 8;   // As staging: row 0..63 (+64), 8 k
  const int ldA = wave * 512;
  const int dg = tid & 31, kp = tid >> 5;  // Bs staging: 4d x 4hp per thread
  f32x4 acc[4][4] = {};

  const _Float16* gA = &st[((size_t)b * E_ + eh * 128 + ar) * HWP_ + ac];
  f16x4 h0, h1, h2, h3;

#define K2_STAGEA(buf, kk) do { \
    gld_lds16(gA + (kk),                      &As[buf][ldA]); \
    gld_lds16(gA + (size_t)64 * HWP_ + (kk),  &As[buf][2048 + ldA]); \
  } while (0)

#define K2_LOADB(kk) do { \
    const _Float16* bsrc = &xf[((size_t)b * HWP_ + (kk) + 4 * kp) * D_ + d0 + 4 * dg]; \
    h0 = *(const f16x4*)&bsrc[0]; \
    h1 = *(const f16x4*)&bsrc[D_]; \
    h2 = *(const f16x4*)&bsrc[2 * D_]; \
    h3 = *(const f16x4*)&bsrc[3 * D_]; \
  } while (0)

#define K2_WRITEB(buf) do { \
    _Pragma("unroll") \
    for (int j = 0; j < 4; j++) { \
      f16x4 o; \
      o[0] = h0[j]; o[1] = h1[j]; o[2] = h2[j]; o[3] = h3[j]; \
      *(f16x4*)&Bs[buf][(4 * dg + j) * 40 + 4 * kp] = o; \
    } \
  } while (0)

  K2_STAGEA(0, 0);
  K2_LOADB(0);
  K2_WRITEB(0);
  __syncthreads();

  int cur = 0;
  for (int k0 = 0; k0 < HWP_; k0 += 32) {
    const bool have = (k0 + 32 < HWP_);
    if (have) {
      K2_STAGEA(cur ^ 1, k0 + 32);
      K2_LOADB(k0 + 32);
    }
    f16x8 af[4], bfr[4];
#pragma unroll
    for (int t = 0; t < 4; t++) {
      af[t]  = *(const f16x8*)&As[cur][(WEl + t * 16 + l15) * 32 + q * 8];
      bfr[t] = *(const f16x8*)&Bs[cur][(WD + t * 16 + l15) * 40 + q * 8];
    }
#pragma unroll
    for (int mt = 0; mt < 4; mt++)
#pragma unroll
      for (int nt = 0; nt < 4; nt++)
        acc[mt][nt] = __builtin_amdgcn_mfma_f32_16x16x32_f16(af[mt], bfr[nt], acc[mt][nt], 0, 0, 0);
    if (have) K2_WRITEB(cur ^ 1);
    __syncthreads();
    cur ^= 1;
  }
#undef K2_STAGEA
#undef K2_LOADB
#undef K2_WRITEB

#pragma unroll
  for (int mt = 0; mt < 4; mt++)
#pragma unroll
    for (int nt = 0; nt < 4; nt++) {
      int d = d0 + WD + nt * 16 + l15;
#pragma unroll
      for (int r = 0; r < 4; r++) {
        int e = eh * 128 + WEl + mt * 16 + q * 4 + r;
        g[((size_t)b * E_ + e) * D_ + d] = (_Float16)acc[mt][nt][r];
      }
    }
}

// ---------------- K3: partials, 512 threads, lm_w on the fly, f16 (R14) -----------
__global__ __launch_bounds__(512) void k3_mfma(const _Float16* __restrict__ g,
                                               const float* __restrict__ lmw,
                                               float* __restrict__ part) {
  __shared__ float sp[B_ * C_];
  const int tid = threadIdx.x;
  const int wave = tid >> 6, lane = tid & 63;
  const int q = lane >> 4, l15 = lane & 15;
  const int e = blockIdx.x;                 // 0..255
  f32x4 acc[4] = {};

  for (int i = tid; i < B_ * C_; i += 512) sp[i] = 0.0f;

#pragma unroll
  for (int ks = 0; ks < 3; ks++) {
    int d = wave * 96 + ks * 32 + q * 8;
    size_t k = (size_t)e * D_ + d;
    f16x8 bfrag;
    if (l15 < C_) {
      const float* bp = &lmw[((size_t)e * C_ + l15) * D_ + d];
      float4 b0 = *(const float4*)&bp[0];
      float4 b1 = *(const float4*)&bp[4];
      float bb[8] = {b0.x, b0.y, b0.z, b0.w, b1.x, b1.y, b1.z, b1.w};
#pragma unroll
      for (int j = 0; j < 8; j++) bfrag[j] = (_Float16)bb[j];
    } else {
#pragma unroll
      for (int j = 0; j < 8; j++) bfrag[j] = (_Float16)0.0f;
    }
#pragma unroll
    for (int mt = 0; mt < 4; mt++) {
      f16x8 afrag = *(const f16x8*)&g[(size_t)(mt * 16 + l15) * K3K_ + k];
      acc[mt] = __builtin_amdgcn_mfma_f32_16x16x32_f16(afrag, bfrag, acc[mt], 0, 0, 0);
    }
  }
  __syncthreads();
  if (l15 < C_) {
#pragma unroll
    for (int mt = 0; mt < 4; mt++)
#pragma unroll
      for (int r = 0; r < 4; r++) {
        int b = mt * 16 + q * 4 + r;
        atomicAdd(&sp[b * C_ + l15], acc[mt][r]);   // LDS atomics only
      }
  }
  __syncthreads();
  for (int i = tid; i < B_ * C_; i += 512)
    part[(size_t)blockIdx.x * (B_ * C_) + i] = sp[i];
}

// ---------------- K4: reduce 256 partials -> out ----------------
__global__ __launch_bounds__(256) void k4_reduce(const float* __restrict__ part,
                                                 float* __restrict__ out) {
  __shared__ float sp[256];
  const int b = blockIdx.x;
  const int tid = threadIdx.x;
  const int c = tid & 15, g16 = tid >> 4;   // 16 groups x 16 c-slots
  float s = 0.0f;
  if (c < C_) {
#pragma unroll
    for (int j = 0; j < 16; j++)
      s += part[(size_t)(g16 + 16 * j) * (B_ * C_) + b * C_ + c];
  }
  sp[tid] = s;
  __syncthreads();
  if (tid < C_) {
    float t = 0.0f;
#pragma unroll
    for (int j = 0; j < 16; j++) t += sp[j * 16 + tid];
    out[b * C_ + tid] = t * (1.0f / (196.0f * 256.0f));
  }
}

extern "C" void kernel_launch(void* const* d_in, const int* in_sizes, int n_in,
                              void* d_out, int out_size, void* d_ws, size_t ws_size,
                              hipStream_t stream) {
  const float* x    = (const float*)d_in[0];   // (64,196,768)
  const float* ag_w = (const float*)d_in[1];   // (256,768)
  const float* ag_b = (const float*)d_in[2];   // (256,)
  const float* lm_w = (const float*)d_in[3];   // (2560,768)
  float* out = (float*)d_out;                  // (64,10)

  char* ws = (char*)d_ws;
  const size_t W_BYTES  = (size_t)E_ * D_ * 2;
  const size_t ST_BYTES = (size_t)B_ * E_ * HWP_ * 2;
  const size_t G_BYTES  = (size_t)B_ * E_ * D_ * 2;
  const size_t XF_BYTES = (size_t)MP_ * D_ * 2;          // 22 MB padded f16 x
  _Float16* w16 = (_Float16*)(ws);
  _Float16* st  = (_Float16*)(ws + W_BYTES);
  _Float16* gb  = (_Float16*)(ws + W_BYTES + ST_BYTES);
  _Float16* xf  = (_Float16*)(ws + W_BYTES + ST_BYTES + G_BYTES);
  float*  part  = (float*)(ws + W_BYTES + ST_BYTES + G_BYTES + XF_BYTES);

  // 192 blocks w16 + 10752 blocks xf (MP_*D_/4/256)
  k0_prep<<<dim3(192 + (MP_ * D_) / 4 / 256), dim3(256), 0, stream>>>(x, ag_w, xf, w16);
  k1_signs<<<dim3(MP_ / 64), dim3(256), 0, stream>>>(xf, w16, ag_b, st);
  k2_g<<<dim3(12 * B_), dim3(256), 0, stream>>>(st, xf, gb);
  k3_mfma<<<dim3(K3NB_), dim3(512), 0, stream>>>(gb, lm_w, part);
  k4_reduce<<<dim3(B_), dim3(256), 0, stream>>>(part, out);
}